// Round 8
// baseline (357.140 us; speedup 1.0000x reference)
//
#include <hip/hip_runtime.h>

#define DEVINL __device__ __forceinline__

typedef __attribute__((ext_vector_type(8))) short short8;
typedef __attribute__((ext_vector_type(4))) short sh4;
typedef __attribute__((ext_vector_type(4))) float floatx4;

constexpr int S_LEN = 2048;
constexpr int DM    = 1024;
constexpr int NHEAD = 16;
constexpr int DHEAD = 64;
constexpr int BATCH = 2;
constexpr int MROWS = BATCH * S_LEN; // 4096
constexpr float LOG2E = 1.44269504f;
// fixed-max softmax: p = exp2(s_raw*0.125*LOG2E - 24*LOG2E); normalization cancels in O/l.
constexpr float SM_C1 = 0.125f * LOG2E;
constexpr float SM_C2 = -24.0f * LOG2E;
constexpr int KSTR = 72;  // K tile LDS row stride (shorts)
constexpr int VSTR = 70;  // V^T tile LDS row stride (shorts) — 35 words: 3*l16 bank rotate

// 16x16x16 bf16 MFMA (A/B = 4 bf16 = 2 VGPR). No __has_builtin guard — amdgcn
// builtins are aux-target in the host pass (guard returns false there).
#define MFMA16(a, b, c) __builtin_amdgcn_mfma_f32_16x16x16bf16_1k(a, b, c, 0, 0, 0)

DEVINL unsigned short f2bf(float x) {  // RNE
  union { float f; unsigned u; } un; un.f = x;
  unsigned u = un.u;
  return (unsigned short)((u + 0x7fffu + ((u >> 16) & 1u)) >> 16);
}
DEVINL unsigned short f2bf_fast(float x) {  // round-half-up (x >= 0)
  union { float f; unsigned u; } un; un.f = x;
  return (unsigned short)((un.u + 0x8000u) >> 16);
}

// ---------------- fp32 -> bf16 convert, 3 tensors in one launch ----------------
__global__ __launch_bounds__(256) void conv3_kernel(const float* __restrict__ s0,
                                                    const float* __restrict__ s1,
                                                    const float* __restrict__ s2,
                                                    unsigned short* __restrict__ d0,
                                                    unsigned short* __restrict__ d1,
                                                    unsigned short* __restrict__ d2) {
  const float* s = blockIdx.y == 0 ? s0 : (blockIdx.y == 1 ? s1 : s2);
  unsigned short* d = blockIdx.y == 0 ? d0 : (blockIdx.y == 1 ? d1 : d2);
  int i = (blockIdx.x * 256 + threadIdx.x) * 4;
  float4 v = *(const float4*)(s + i);
  unsigned lo = (unsigned)f2bf(v.x) | ((unsigned)f2bf(v.y) << 16);
  unsigned hi = (unsigned)f2bf(v.z) | ((unsigned)f2bf(v.w) << 16);
  *(uint2*)(d + i) = make_uint2(lo, hi);
}

// ------------- fp32 W[K][N] -> bf16 Wt[N][K], 4 weights in one launch -------------
__global__ __launch_bounds__(256) void trans4_kernel(const float* __restrict__ W0,
                                                     const float* __restrict__ W1,
                                                     const float* __restrict__ W2,
                                                     const float* __restrict__ W3,
                                                     unsigned short* __restrict__ T0,
                                                     unsigned short* __restrict__ T1,
                                                     unsigned short* __restrict__ T2,
                                                     unsigned short* __restrict__ T3) {
  const float* W = blockIdx.z == 0 ? W0 : (blockIdx.z == 1 ? W1 : (blockIdx.z == 2 ? W2 : W3));
  unsigned short* Wt = blockIdx.z == 0 ? T0 : (blockIdx.z == 1 ? T1 : (blockIdx.z == 2 ? T2 : T3));
  __shared__ unsigned short tile[32][33];
  int t = threadIdx.x;
  int c = t & 31, r0 = t >> 5;
  int nB = blockIdx.x * 32, kB = blockIdx.y * 32;
  for (int i = 0; i < 4; ++i) {
    int r = r0 + i * 8;
    tile[r][c] = f2bf(W[(size_t)(kB + r) * DM + nB + c]);
  }
  __syncthreads();
  for (int i = 0; i < 4; ++i) {
    int r = r0 + i * 8;
    Wt[(size_t)(nB + r) * DM + kB + c] = tile[c][r];
  }
}

// ------------- async 16B global->LDS -------------
DEVINL void load_lds16(const unsigned short* g, unsigned short* l) {
  __builtin_amdgcn_global_load_lds((const __attribute__((address_space(1))) unsigned int*)g,
                                   (__attribute__((address_space(3))) unsigned int*)l,
                                   16, 0, 0);
}

// ------------- GEMM body (128x128 tile): C = A[4096][1024] @ Bt^T -------------
// MODE 0: bf16 row-major out; MODE 1: fp32 row-major out; MODE 2: bf16 V-transposed out
// (vt[(b*16+h)*64+d][s], fusing the V-transpose into the V projection).
template <int MODE>
DEVINL void gemm_body(const unsigned short* __restrict__ A,
                      const unsigned short* __restrict__ Bt,
                      void* __restrict__ Cout) {
  constexpr int K = 1024, N = 1024;
  __shared__ alignas(16) unsigned short As[128 * 32];
  __shared__ alignas(16) unsigned short Bs[128 * 32];
  const int tid  = threadIdx.x;
  const int wave = tid >> 6, lane = tid & 63;
  const int quad = lane >> 4, l16 = lane & 15;
  const int mBase = blockIdx.y * 128, nBase = blockIdx.x * 128;
  const int wm = (wave >> 1) * 64, wn = (wave & 1) * 64;
  const int sr = lane >> 2;
  const int sc = (lane & 3) * 8;
  floatx4 acc[4][4] = {};

  for (int k0 = 0; k0 < K; k0 += 32) {
    __syncthreads();
#pragma unroll
    for (int j = 0; j < 2; ++j) {
      int row = wave * 32 + j * 16 + sr;
      load_lds16(A  + (size_t)(mBase + row) * K + k0 + sc, As + (wave * 32 + j * 16) * 32);
      load_lds16(Bt + (size_t)(nBase + row) * K + k0 + sc, Bs + (wave * 32 + j * 16) * 32);
    }
    __syncthreads();
    short8 af[4], bfr[4];
#pragma unroll
    for (int mt = 0; mt < 4; ++mt) af[mt]  = *(const short8*)&As[(wm + mt * 16 + l16) * 32 + quad * 8];
#pragma unroll
    for (int nt = 0; nt < 4; ++nt) bfr[nt] = *(const short8*)&Bs[(wn + nt * 16 + l16) * 32 + quad * 8];
#pragma unroll
    for (int mt = 0; mt < 4; ++mt)
#pragma unroll
      for (int nt = 0; nt < 4; ++nt)
        acc[mt][nt] = __builtin_amdgcn_mfma_f32_16x16x32_bf16(af[mt], bfr[nt], acc[mt][nt], 0, 0, 0);
  }

#pragma unroll
  for (int mt = 0; mt < 4; ++mt)
#pragma unroll
    for (int nt = 0; nt < 4; ++nt) {
      const int m = mBase + wm + mt * 16 + quad * 4;   // +r
      const int n = nBase + wn + nt * 16 + l16;
      if (MODE == 2) {
        const int bq = m >> 11, s = m & 2047;
        const int hh = n >> 6,  d = n & 63;
        unsigned short w4[4];
#pragma unroll
        for (int r = 0; r < 4; ++r) w4[r] = f2bf(acc[mt][nt][r]);
        *(uint2*)&((unsigned short*)Cout)[((size_t)((bq * 16 + hh) * 64 + d)) * S_LEN + s] =
            *(const uint2*)w4;
      } else {
#pragma unroll
        for (int r = 0; r < 4; ++r) {
          if (MODE == 0) ((unsigned short*)Cout)[(size_t)(m + r) * N + n] = f2bf(acc[mt][nt][r]);
          else           ((float*)Cout)[(size_t)(m + r) * N + n]          = acc[mt][nt][r];
        }
      }
    }
}

__global__ __launch_bounds__(256) void gemm_qkv(const unsigned short* __restrict__ A0,
                                                const unsigned short* __restrict__ A1,
                                                const unsigned short* __restrict__ A2,
                                                const unsigned short* __restrict__ B0,
                                                const unsigned short* __restrict__ B1,
                                                const unsigned short* __restrict__ B2,
                                                unsigned short* __restrict__ C0,
                                                unsigned short* __restrict__ C1,
                                                unsigned short* __restrict__ C2) {
  const int z = blockIdx.z;
  if (z == 2)      gemm_body<2>(A2, B2, C2);   // V: write transposed vt directly
  else if (z == 1) gemm_body<0>(A1, B1, C1);
  else             gemm_body<0>(A0, B0, C0);
}

// ------------- output GEMM, 64x128 tile (512 blocks -> 2/CU overlap) -------------
__global__ __launch_bounds__(256) void gemm_out64(const unsigned short* __restrict__ A,
                                                  const unsigned short* __restrict__ Bt,
                                                  float* __restrict__ C) {
  constexpr int K = 1024, N = 1024;
  __shared__ alignas(16) unsigned short As[64 * 32];
  __shared__ alignas(16) unsigned short Bs[128 * 32];
  const int tid  = threadIdx.x;
  const int wave = tid >> 6, lane = tid & 63;
  const int quad = lane >> 4, l16 = lane & 15;
  const int mBase = blockIdx.y * 64, nBase = blockIdx.x * 128;
  const int wm = (wave >> 1) * 32, wn = (wave & 1) * 64;
  const int sr = lane >> 2;
  const int sc = (lane & 3) * 8;
  floatx4 acc[2][4] = {};

  for (int k0 = 0; k0 < K; k0 += 32) {
    __syncthreads();
    load_lds16(A + (size_t)(mBase + wave * 16 + sr) * K + k0 + sc, As + (wave * 16) * 32);
#pragma unroll
    for (int j = 0; j < 2; ++j) {
      int row = wave * 32 + j * 16 + sr;
      load_lds16(Bt + (size_t)(nBase + row) * K + k0 + sc, Bs + (wave * 32 + j * 16) * 32);
    }
    __syncthreads();
    short8 af[2], bfr[4];
#pragma unroll
    for (int mt = 0; mt < 2; ++mt) af[mt]  = *(const short8*)&As[(wm + mt * 16 + l16) * 32 + quad * 8];
#pragma unroll
    for (int nt = 0; nt < 4; ++nt) bfr[nt] = *(const short8*)&Bs[(wn + nt * 16 + l16) * 32 + quad * 8];
#pragma unroll
    for (int mt = 0; mt < 2; ++mt)
#pragma unroll
      for (int nt = 0; nt < 4; ++nt)
        acc[mt][nt] = __builtin_amdgcn_mfma_f32_16x16x32_bf16(af[mt], bfr[nt], acc[mt][nt], 0, 0, 0);
  }

#pragma unroll
  for (int mt = 0; mt < 2; ++mt)
#pragma unroll
    for (int nt = 0; nt < 4; ++nt)
#pragma unroll
      for (int r = 0; r < 4; ++r) {
        int m = mBase + wm + mt * 16 + quad * 4 + r;
        int n = nBase + wn + nt * 16 + l16;
        C[(size_t)m * N + n] = acc[mt][nt][r];
      }
}

// ------------- causal flash attention: LDS-staged K/V + register-resident P -------------
// S^T trick: QK as A=K,B=Q -> lane holds P[q=l16][s=quad*4+r] = A-operand layout of
// mfma 16x16x16 for PV -> P never leaves registers. K/V staged coalesced to LDS
// (reg double-buffered); each wave reads only its own 16-wide s-strip fragments
// (2x ds_read_b128 + 4x ds_read_b64 per iter). Wave-partial O/l merged additively
// (fixed-max softmax) in an LDS epilogue.
__global__ __launch_bounds__(256, 4) void attn_kernel(const unsigned short* __restrict__ Qp,
                                                      const unsigned short* __restrict__ Kp,
                                                      const unsigned short* __restrict__ Vtg,
                                                      unsigned short* __restrict__ ctx) {
  const int qt = 31 - blockIdx.x;        // heavy blocks dispatch first
  const int bh = blockIdx.y;
  const int b  = bh >> 4, h = bh & 15;
  const int tid = threadIdx.x;
  const int w = tid >> 6, lane = tid & 63;
  const int quad = lane >> 4, l16 = lane & 15;
  const int Q0 = qt * 64;
  const int nT = qt + 1;

  __shared__ alignas(16) unsigned short Ks[64 * KSTR];   // K tile [s][d]
  __shared__ alignas(16) unsigned short Vs[64 * VSTR];   // V^T tile [d][s]
  __shared__ float rsL[4][4][16];                        // [wave][nt][q16]
  __shared__ alignas(16) float Ored[4][4][16][16];       // [wave][dt][d16][q16]

  const unsigned short* Kbh = Kp  + (size_t)(b * S_LEN) * DM + h * DHEAD;
  const unsigned short* Vbh = Vtg + (size_t)(bh * DHEAD) * S_LEN;

  // staging addresses (fixed per thread): K rows sr/sr+32, V^T rows sr/sr+32
  const int sr = tid >> 3, sc8 = (tid & 7) * 8;
  const unsigned short* kg = Kbh + (size_t)sr * DM + sc8;
  const unsigned short* vg = Vbh + (size_t)sr * S_LEN + sc8;
  unsigned short* ksl = Ks + sr * KSTR + sc8;
  unsigned short* vsl = Vs + sr * VSTR + sc8;

  // Q fragments (B-operand: n=l16 -> q, k=quad*8+j -> d), loaded once
  short8 qB[4][2];
#pragma unroll
  for (int nt = 0; nt < 4; ++nt) {
    const size_t qr = ((size_t)(b * S_LEN + Q0 + nt * 16 + l16)) * DM + h * DHEAD + quad * 8;
    qB[nt][0] = *(const short8*)&Qp[qr];
    qB[nt][1] = *(const short8*)&Qp[qr + 32];
  }

  floatx4 o[4][4] = {};
  float rs[4] = {0.f, 0.f, 0.f, 0.f};

  // preload tile 0 into registers
  uint4 kr0 = *(const uint4*)kg;
  uint4 kr1 = *(const uint4*)(kg + (size_t)32 * DM);
  uint4 vr0 = *(const uint4*)vg;
  uint4 vr1 = *(const uint4*)(vg + (size_t)32 * S_LEN);

  for (int t = 0; t < nT; ++t) {
    __syncthreads();
    *(uint4*)ksl               = kr0;
    *(uint4*)(ksl + 32 * KSTR) = kr1;
    *(uint4*)vsl               = vr0;
    *(uint4*)(vsl + 32 * VSTR) = vr1;
    __syncthreads();

    // prefetch next tile (registers only; no LDS write until next iter's barrier)
    if (t + 1 < nT) {
      const int kbn = (t + 1) * 64;
      kr0 = *(const uint4*)(kg + (size_t)kbn * DM);
      kr1 = *(const uint4*)(kg + (size_t)(kbn + 32) * DM);
      vr0 = *(const uint4*)(vg + kbn);
      vr1 = *(const uint4*)(vg + (size_t)32 * S_LEN + kbn);
    }

    // fragments from LDS: this wave's s-strip only
    short8 kc0 = *(const short8*)&Ks[(w * 16 + l16) * KSTR + quad * 8];
    short8 kc1 = *(const short8*)&Ks[(w * 16 + l16) * KSTR + 32 + quad * 8];
    sh4 vv[4];
#pragma unroll
    for (int dt = 0; dt < 4; ++dt)
      vv[dt] = *(const sh4*)&Vs[(dt * 16 + l16) * VSTR + w * 16 + quad * 4];

    const bool masked = (t == nT - 1);
    const int sbase = w * 16 + quad * 4;   // s - kb, + r

#pragma unroll
    for (int nt = 0; nt < 4; ++nt) {
      floatx4 sc = {};
      sc = __builtin_amdgcn_mfma_f32_16x16x32_bf16(kc0, qB[nt][0], sc, 0, 0, 0);
      sc = __builtin_amdgcn_mfma_f32_16x16x32_bf16(kc1, qB[nt][1], sc, 0, 0, 0);
      const int qoff = nt * 16 + l16;      // q - Q0
      sh4 pa;
      float acc = 0.f;
#pragma unroll
      for (int r = 0; r < 4; ++r) {
        float p = __builtin_amdgcn_exp2f(fmaf(sc[r], SM_C1, SM_C2));
        if (masked && (sbase + r > qoff)) p = 0.f;
        acc += p;
        pa[r] = (short)f2bf_fast(p);
      }
      rs[nt] += acc;
#pragma unroll
      for (int dt = 0; dt < 4; ++dt)
        o[nt][dt] = MFMA16(pa, vv[dt], o[nt][dt]);
    }
  }

  // ---- epilogue: merge 4 wave-partials (additive), normalize, write ctx ----
#pragma unroll
  for (int nt = 0; nt < 4; ++nt) {
    rs[nt] += __shfl_xor(rs[nt], 16, 64);
    rs[nt] += __shfl_xor(rs[nt], 32, 64);
  }
  if (quad == 0) {
#pragma unroll
    for (int nt = 0; nt < 4; ++nt) rsL[w][nt][l16] = rs[nt];
  }

  for (int nt = 0; nt < 4; ++nt) {
    __syncthreads();
#pragma unroll
    for (int dt = 0; dt < 4; ++dt)
      *(floatx4*)&Ored[w][dt][l16][quad * 4] = o[nt][dt];
    __syncthreads();
    // wave w handles d-tile dt == w; lane -> (q = quad*4+j, d = w*16+l16)
    floatx4 acc = {};
#pragma unroll
    for (int w2 = 0; w2 < 4; ++w2) {
      floatx4 v = *(const floatx4*)&Ored[w2][w][l16][quad * 4];
#pragma unroll
      for (int j = 0; j < 4; ++j) acc[j] += v[j];
    }
#pragma unroll
    for (int j = 0; j < 4; ++j) {
      const int q16 = quad * 4 + j;
      float l = rsL[0][nt][q16] + rsL[1][nt][q16] + rsL[2][nt][q16] + rsL[3][nt][q16];
      const size_t row = (size_t)(b * S_LEN + Q0 + nt * 16 + q16);
      ctx[row * DM + h * DHEAD + w * 16 + l16] = f2bf(acc[j] / l);
    }
  }
}

extern "C" void kernel_launch(void* const* d_in, const int* in_sizes, int n_in,
                              void* d_out, int out_size, void* d_ws, size_t ws_size,
                              hipStream_t stream) {
  const float* Xq = (const float*)d_in[0];
  const float* Xk = (const float*)d_in[1];
  const float* Xv = (const float*)d_in[2];
  const float* Wq = (const float*)d_in[5];
  const float* Wk = (const float*)d_in[6];
  const float* Wv = (const float*)d_in[7];
  const float* Wo = (const float*)d_in[8];
  float* out = (float*)d_out;

  char* ws = (char*)d_ws;
  constexpr size_t XBYTES = (size_t)MROWS * DM * 2;  // 8 MiB
  constexpr size_t WBYTES = (size_t)DM * DM * 2;     // 2 MiB
  unsigned short* xq_bf = (unsigned short*)(ws);
  unsigned short* xk_bf = (unsigned short*)(ws + XBYTES);
  unsigned short* xv_bf = (unsigned short*)(ws + 2 * XBYTES);
  unsigned short* wqt   = (unsigned short*)(ws + 3 * XBYTES);
  unsigned short* wkt   = (unsigned short*)(ws + 3 * XBYTES + WBYTES);
  unsigned short* wvt   = (unsigned short*)(ws + 3 * XBYTES + 2 * WBYTES);
  unsigned short* wot   = (unsigned short*)(ws + 3 * XBYTES + 3 * WBYTES);
  unsigned short* qp    = (unsigned short*)(ws + 3 * XBYTES + 4 * WBYTES);
  unsigned short* kp    = (unsigned short*)(ws + 4 * XBYTES + 4 * WBYTES);
  unsigned short* vt    = (unsigned short*)(ws + 5 * XBYTES + 4 * WBYTES); // V^T, written by V-GEMM
  unsigned short* ctx   = xq_bf;  // dead after Q projection

  const int nX = MROWS * DM;
  conv3_kernel<<<dim3(nX / 1024, 3), 256, 0, stream>>>(Xq, Xk, Xv, xq_bf, xk_bf, xv_bf);
  trans4_kernel<<<dim3(32, 32, 4), 256, 0, stream>>>(Wq, Wk, Wv, Wo, wqt, wkt, wvt, wot);

  gemm_qkv<<<dim3(DM / 128, MROWS / 128, 3), 256, 0, stream>>>(
      xq_bf, xk_bf, xv_bf, wqt, wkt, wvt, qp, kp, vt);

  attn_kernel<<<dim3(32, BATCH * NHEAD), 256, 0, stream>>>(qp, kp, vt, ctx);

  gemm_out64<<<dim3(DM / 128, MROWS / 64), 256, 0, stream>>>(ctx, wot, out);
}

// Round 9
// 261.661 us; speedup vs baseline: 1.3649x; 1.3649x over previous
//
#include <hip/hip_runtime.h>

#define DEVINL __device__ __forceinline__

typedef __attribute__((ext_vector_type(8))) short short8;
typedef __attribute__((ext_vector_type(4))) short sh4;
typedef __attribute__((ext_vector_type(4))) float floatx4;

constexpr int S_LEN = 2048;
constexpr int DM    = 1024;
constexpr int NHEAD = 16;
constexpr int DHEAD = 64;
constexpr int BATCH = 2;
constexpr int MROWS = BATCH * S_LEN; // 4096
constexpr float LOG2E = 1.44269504f;
// fixed-max softmax: p = exp2(s_raw*0.125*LOG2E - 24*LOG2E); normalization cancels in O/l.
constexpr float SM_C1 = 0.125f * LOG2E;
constexpr float SM_C2 = -24.0f * LOG2E;
constexpr int KSTR = 72;  // K tile LDS row stride (shorts)
constexpr int VSTR = 70;  // V^T tile LDS row stride (shorts)

// 16x16x16 bf16 MFMA (A/B = 4 bf16 = 2 VGPR). No __has_builtin guard — amdgcn
// builtins are aux-target in the host pass (guard returns false there).
#define MFMA16(a, b, c) __builtin_amdgcn_mfma_f32_16x16x16bf16_1k(a, b, c, 0, 0, 0)

DEVINL unsigned short f2bf(float x) {  // RNE
  union { float f; unsigned u; } un; un.f = x;
  unsigned u = un.u;
  return (unsigned short)((u + 0x7fffu + ((u >> 16) & 1u)) >> 16);
}
DEVINL unsigned short f2bf_fast(float x) {  // round-half-up (x >= 0)
  union { float f; unsigned u; } un; un.f = x;
  return (unsigned short)((un.u + 0x8000u) >> 16);
}

// ---------------- fp32 -> bf16 convert, 3 tensors in one launch ----------------
__global__ __launch_bounds__(256) void conv3_kernel(const float* __restrict__ s0,
                                                    const float* __restrict__ s1,
                                                    const float* __restrict__ s2,
                                                    unsigned short* __restrict__ d0,
                                                    unsigned short* __restrict__ d1,
                                                    unsigned short* __restrict__ d2) {
  const float* s = blockIdx.y == 0 ? s0 : (blockIdx.y == 1 ? s1 : s2);
  unsigned short* d = blockIdx.y == 0 ? d0 : (blockIdx.y == 1 ? d1 : d2);
  int i = (blockIdx.x * 256 + threadIdx.x) * 4;
  float4 v = *(const float4*)(s + i);
  unsigned lo = (unsigned)f2bf(v.x) | ((unsigned)f2bf(v.y) << 16);
  unsigned hi = (unsigned)f2bf(v.z) | ((unsigned)f2bf(v.w) << 16);
  *(uint2*)(d + i) = make_uint2(lo, hi);
}

// ------------- fp32 W[K][N] -> bf16 Wt[N][K], 4 weights in one launch -------------
__global__ __launch_bounds__(256) void trans4_kernel(const float* __restrict__ W0,
                                                     const float* __restrict__ W1,
                                                     const float* __restrict__ W2,
                                                     const float* __restrict__ W3,
                                                     unsigned short* __restrict__ T0,
                                                     unsigned short* __restrict__ T1,
                                                     unsigned short* __restrict__ T2,
                                                     unsigned short* __restrict__ T3) {
  const float* W = blockIdx.z == 0 ? W0 : (blockIdx.z == 1 ? W1 : (blockIdx.z == 2 ? W2 : W3));
  unsigned short* Wt = blockIdx.z == 0 ? T0 : (blockIdx.z == 1 ? T1 : (blockIdx.z == 2 ? T2 : T3));
  __shared__ unsigned short tile[32][33];
  int t = threadIdx.x;
  int c = t & 31, r0 = t >> 5;
  int nB = blockIdx.x * 32, kB = blockIdx.y * 32;
  for (int i = 0; i < 4; ++i) {
    int r = r0 + i * 8;
    tile[r][c] = f2bf(W[(size_t)(kB + r) * DM + nB + c]);
  }
  __syncthreads();
  for (int i = 0; i < 4; ++i) {
    int r = r0 + i * 8;
    Wt[(size_t)(nB + r) * DM + kB + c] = tile[c][r];
  }
}

// ------------- async 16B global->LDS -------------
DEVINL void load_lds16(const unsigned short* g, unsigned short* l) {
  __builtin_amdgcn_global_load_lds((const __attribute__((address_space(1))) unsigned int*)g,
                                   (__attribute__((address_space(3))) unsigned int*)l,
                                   16, 0, 0);
}

// ------------- GEMM body (128x128 tile): C = A[4096][1024] @ Bt^T -------------
// MODE 0: bf16 row-major out; MODE 1: fp32 row-major out; MODE 2: bf16 V-transposed out
// (vt[(b*16+h)*64+d][s], fusing the V-transpose into the V projection).
template <int MODE>
DEVINL void gemm_body(const unsigned short* __restrict__ A,
                      const unsigned short* __restrict__ Bt,
                      void* __restrict__ Cout) {
  constexpr int K = 1024, N = 1024;
  __shared__ alignas(16) unsigned short As[128 * 32];
  __shared__ alignas(16) unsigned short Bs[128 * 32];
  const int tid  = threadIdx.x;
  const int wave = tid >> 6, lane = tid & 63;
  const int quad = lane >> 4, l16 = lane & 15;
  const int mBase = blockIdx.y * 128, nBase = blockIdx.x * 128;
  const int wm = (wave >> 1) * 64, wn = (wave & 1) * 64;
  const int sr = lane >> 2;
  const int sc = (lane & 3) * 8;
  floatx4 acc[4][4] = {};

  for (int k0 = 0; k0 < K; k0 += 32) {
    __syncthreads();
#pragma unroll
    for (int j = 0; j < 2; ++j) {
      int row = wave * 32 + j * 16 + sr;
      load_lds16(A  + (size_t)(mBase + row) * K + k0 + sc, As + (wave * 32 + j * 16) * 32);
      load_lds16(Bt + (size_t)(nBase + row) * K + k0 + sc, Bs + (wave * 32 + j * 16) * 32);
    }
    __syncthreads();
    short8 af[4], bfr[4];
#pragma unroll
    for (int mt = 0; mt < 4; ++mt) af[mt]  = *(const short8*)&As[(wm + mt * 16 + l16) * 32 + quad * 8];
#pragma unroll
    for (int nt = 0; nt < 4; ++nt) bfr[nt] = *(const short8*)&Bs[(wn + nt * 16 + l16) * 32 + quad * 8];
#pragma unroll
    for (int mt = 0; mt < 4; ++mt)
#pragma unroll
      for (int nt = 0; nt < 4; ++nt)
        acc[mt][nt] = __builtin_amdgcn_mfma_f32_16x16x32_bf16(af[mt], bfr[nt], acc[mt][nt], 0, 0, 0);
  }

#pragma unroll
  for (int mt = 0; mt < 4; ++mt)
#pragma unroll
    for (int nt = 0; nt < 4; ++nt) {
      const int m = mBase + wm + mt * 16 + quad * 4;   // +r
      const int n = nBase + wn + nt * 16 + l16;
      if (MODE == 2) {
        const int bq = m >> 11, s = m & 2047;
        const int hh = n >> 6,  d = n & 63;
        unsigned short w4[4];
#pragma unroll
        for (int r = 0; r < 4; ++r) w4[r] = f2bf(acc[mt][nt][r]);
        *(uint2*)&((unsigned short*)Cout)[((size_t)((bq * 16 + hh) * 64 + d)) * S_LEN + s] =
            *(const uint2*)w4;
      } else {
#pragma unroll
        for (int r = 0; r < 4; ++r) {
          if (MODE == 0) ((unsigned short*)Cout)[(size_t)(m + r) * N + n] = f2bf(acc[mt][nt][r]);
          else           ((float*)Cout)[(size_t)(m + r) * N + n]          = acc[mt][nt][r];
        }
      }
    }
}

__global__ __launch_bounds__(256) void gemm_qkv(const unsigned short* __restrict__ A0,
                                                const unsigned short* __restrict__ A1,
                                                const unsigned short* __restrict__ A2,
                                                const unsigned short* __restrict__ B0,
                                                const unsigned short* __restrict__ B1,
                                                const unsigned short* __restrict__ B2,
                                                unsigned short* __restrict__ C0,
                                                unsigned short* __restrict__ C1,
                                                unsigned short* __restrict__ C2) {
  const int z = blockIdx.z;
  if (z == 2)      gemm_body<2>(A2, B2, C2);   // V: write transposed vt directly
  else if (z == 1) gemm_body<0>(A1, B1, C1);
  else             gemm_body<0>(A0, B0, C0);
}

// ------------- output GEMM, 64x128 tile (512 blocks -> 2/CU overlap) -------------
__global__ __launch_bounds__(256) void gemm_out64(const unsigned short* __restrict__ A,
                                                  const unsigned short* __restrict__ Bt,
                                                  float* __restrict__ C) {
  constexpr int K = 1024, N = 1024;
  __shared__ alignas(16) unsigned short As[64 * 32];
  __shared__ alignas(16) unsigned short Bs[128 * 32];
  const int tid  = threadIdx.x;
  const int wave = tid >> 6, lane = tid & 63;
  const int quad = lane >> 4, l16 = lane & 15;
  const int mBase = blockIdx.y * 64, nBase = blockIdx.x * 128;
  const int wm = (wave >> 1) * 32, wn = (wave & 1) * 64;
  const int sr = lane >> 2;
  const int sc = (lane & 3) * 8;
  floatx4 acc[2][4] = {};

  for (int k0 = 0; k0 < K; k0 += 32) {
    __syncthreads();
    load_lds16(A + (size_t)(mBase + wave * 16 + sr) * K + k0 + sc, As + (wave * 16) * 32);
#pragma unroll
    for (int j = 0; j < 2; ++j) {
      int row = wave * 32 + j * 16 + sr;
      load_lds16(Bt + (size_t)(nBase + row) * K + k0 + sc, Bs + (wave * 32 + j * 16) * 32);
    }
    __syncthreads();
    short8 af[2], bfr[4];
#pragma unroll
    for (int mt = 0; mt < 2; ++mt) af[mt]  = *(const short8*)&As[(wm + mt * 16 + l16) * 32 + quad * 8];
#pragma unroll
    for (int nt = 0; nt < 4; ++nt) bfr[nt] = *(const short8*)&Bs[(wn + nt * 16 + l16) * 32 + quad * 8];
#pragma unroll
    for (int mt = 0; mt < 2; ++mt)
#pragma unroll
      for (int nt = 0; nt < 4; ++nt)
        acc[mt][nt] = __builtin_amdgcn_mfma_f32_16x16x32_bf16(af[mt], bfr[nt], acc[mt][nt], 0, 0, 0);
  }

#pragma unroll
  for (int mt = 0; mt < 2; ++mt)
#pragma unroll
    for (int nt = 0; nt < 4; ++nt)
#pragma unroll
      for (int r = 0; r < 4; ++r) {
        int m = mBase + wm + mt * 16 + quad * 4 + r;
        int n = nBase + wn + nt * 16 + l16;
        C[(size_t)m * N + n] = acc[mt][nt][r];
      }
}

// ------------- causal flash attention: LDS-staged K/V + register-resident P -------------
// S^T trick: QK as A=K,B=Q -> lane holds P[q=l16][s=quad*4+r] = A-operand layout of
// mfma 16x16x16 for PV -> P never leaves registers. K/V staged coalesced to LDS
// (reg double-buffered); each wave reads only its own 16-wide s-strip fragments.
// launch_bounds (256,3): 170-reg budget — (256,4) capped at 128 and spilled ~150 MB
// of scratch traffic to HBM (R8: WRITE_SIZE 62 MB, FETCH 166 MB).
__global__ __launch_bounds__(256, 3) void attn_kernel(const unsigned short* __restrict__ Qp,
                                                      const unsigned short* __restrict__ Kp,
                                                      const unsigned short* __restrict__ Vtg,
                                                      unsigned short* __restrict__ ctx) {
  const int qt = 31 - blockIdx.x;        // heavy blocks dispatch first
  const int bh = blockIdx.y;
  const int b  = bh >> 4, h = bh & 15;
  const int tid = threadIdx.x;
  const int w = tid >> 6, lane = tid & 63;
  const int quad = lane >> 4, l16 = lane & 15;
  const int Q0 = qt * 64;
  const int nT = qt + 1;

  __shared__ alignas(16) unsigned short Ks[64 * KSTR];   // K tile [s][d]
  __shared__ alignas(16) unsigned short Vs[64 * VSTR];   // V^T tile [d][s]
  __shared__ float rsL[4][4][16];                        // [wave][nt][q16]
  __shared__ alignas(16) float Ored[4][4][16][16];       // [wave][dt][d16][q16]

  const unsigned short* Kbh = Kp  + (size_t)(b * S_LEN) * DM + h * DHEAD;
  const unsigned short* Vbh = Vtg + (size_t)(bh * DHEAD) * S_LEN;

  // staging addresses (fixed per thread): K rows sr/sr+32, V^T rows sr/sr+32
  const int sr = tid >> 3, sc8 = (tid & 7) * 8;
  const unsigned short* kg = Kbh + (size_t)sr * DM + sc8;
  const unsigned short* vg = Vbh + (size_t)sr * S_LEN + sc8;
  unsigned short* ksl = Ks + sr * KSTR + sc8;
  unsigned short* vsl = Vs + sr * VSTR + sc8;

  // Q fragments (B-operand: n=l16 -> q, k=quad*8+j -> d), loaded once
  short8 qB[4][2];
#pragma unroll
  for (int nt = 0; nt < 4; ++nt) {
    const size_t qr = ((size_t)(b * S_LEN + Q0 + nt * 16 + l16)) * DM + h * DHEAD + quad * 8;
    qB[nt][0] = *(const short8*)&Qp[qr];
    qB[nt][1] = *(const short8*)&Qp[qr + 32];
  }

  floatx4 o[4][4] = {};
  float rs[4] = {0.f, 0.f, 0.f, 0.f};

  // preload tile 0 into registers
  uint4 kr0 = *(const uint4*)kg;
  uint4 kr1 = *(const uint4*)(kg + (size_t)32 * DM);
  uint4 vr0 = *(const uint4*)vg;
  uint4 vr1 = *(const uint4*)(vg + (size_t)32 * S_LEN);

  for (int t = 0; t < nT; ++t) {
    __syncthreads();
    *(uint4*)ksl               = kr0;
    *(uint4*)(ksl + 32 * KSTR) = kr1;
    *(uint4*)vsl               = vr0;
    *(uint4*)(vsl + 32 * VSTR) = vr1;
    __syncthreads();

    // prefetch next tile (registers only; no LDS write until next iter's barrier)
    if (t + 1 < nT) {
      const int kbn = (t + 1) * 64;
      kr0 = *(const uint4*)(kg + (size_t)kbn * DM);
      kr1 = *(const uint4*)(kg + (size_t)(kbn + 32) * DM);
      vr0 = *(const uint4*)(vg + kbn);
      vr1 = *(const uint4*)(vg + (size_t)32 * S_LEN + kbn);
    }

    // fragments from LDS: this wave's s-strip only
    short8 kc0 = *(const short8*)&Ks[(w * 16 + l16) * KSTR + quad * 8];
    short8 kc1 = *(const short8*)&Ks[(w * 16 + l16) * KSTR + 32 + quad * 8];
    sh4 vv[4];
#pragma unroll
    for (int dt = 0; dt < 4; ++dt)
      vv[dt] = *(const sh4*)&Vs[(dt * 16 + l16) * VSTR + w * 16 + quad * 4];

    const bool masked = (t == nT - 1);
    const int sbase = w * 16 + quad * 4;   // s - kb, + r

#pragma unroll
    for (int nt = 0; nt < 4; ++nt) {
      floatx4 sc = {};
      sc = __builtin_amdgcn_mfma_f32_16x16x32_bf16(kc0, qB[nt][0], sc, 0, 0, 0);
      sc = __builtin_amdgcn_mfma_f32_16x16x32_bf16(kc1, qB[nt][1], sc, 0, 0, 0);
      const int qoff = nt * 16 + l16;      // q - Q0
      sh4 pa;
      float acc = 0.f;
#pragma unroll
      for (int r = 0; r < 4; ++r) {
        float p = __builtin_amdgcn_exp2f(fmaf(sc[r], SM_C1, SM_C2));
        if (masked && (sbase + r > qoff)) p = 0.f;
        acc += p;
        pa[r] = (short)f2bf_fast(p);
      }
      rs[nt] += acc;
#pragma unroll
      for (int dt = 0; dt < 4; ++dt)
        o[nt][dt] = MFMA16(pa, vv[dt], o[nt][dt]);
    }
  }

  // ---- epilogue: merge 4 wave-partials (additive), normalize, write ctx ----
#pragma unroll
  for (int nt = 0; nt < 4; ++nt) {
    rs[nt] += __shfl_xor(rs[nt], 16, 64);
    rs[nt] += __shfl_xor(rs[nt], 32, 64);
  }
  if (quad == 0) {
#pragma unroll
    for (int nt = 0; nt < 4; ++nt) rsL[w][nt][l16] = rs[nt];
  }

  for (int nt = 0; nt < 4; ++nt) {
    __syncthreads();
#pragma unroll
    for (int dt = 0; dt < 4; ++dt)
      *(floatx4*)&Ored[w][dt][l16][quad * 4] = o[nt][dt];
    __syncthreads();
    // wave w handles d-tile dt == w; lane -> (q = quad*4+j, d = w*16+l16)
    floatx4 acc = {};
#pragma unroll
    for (int w2 = 0; w2 < 4; ++w2) {
      floatx4 v = *(const floatx4*)&Ored[w2][w][l16][quad * 4];
#pragma unroll
      for (int j = 0; j < 4; ++j) acc[j] += v[j];
    }
#pragma unroll
    for (int j = 0; j < 4; ++j) {
      const int q16 = quad * 4 + j;
      float l = rsL[0][nt][q16] + rsL[1][nt][q16] + rsL[2][nt][q16] + rsL[3][nt][q16];
      const size_t row = (size_t)(b * S_LEN + Q0 + nt * 16 + q16);
      ctx[row * DM + h * DHEAD + w * 16 + l16] = f2bf(acc[j] / l);
    }
  }
}

extern "C" void kernel_launch(void* const* d_in, const int* in_sizes, int n_in,
                              void* d_out, int out_size, void* d_ws, size_t ws_size,
                              hipStream_t stream) {
  const float* Xq = (const float*)d_in[0];
  const float* Xk = (const float*)d_in[1];
  const float* Xv = (const float*)d_in[2];
  const float* Wq = (const float*)d_in[5];
  const float* Wk = (const float*)d_in[6];
  const float* Wv = (const float*)d_in[7];
  const float* Wo = (const float*)d_in[8];
  float* out = (float*)d_out;

  char* ws = (char*)d_ws;
  constexpr size_t XBYTES = (size_t)MROWS * DM * 2;  // 8 MiB
  constexpr size_t WBYTES = (size_t)DM * DM * 2;     // 2 MiB
  unsigned short* xq_bf = (unsigned short*)(ws);
  unsigned short* xk_bf = (unsigned short*)(ws + XBYTES);
  unsigned short* xv_bf = (unsigned short*)(ws + 2 * XBYTES);
  unsigned short* wqt   = (unsigned short*)(ws + 3 * XBYTES);
  unsigned short* wkt   = (unsigned short*)(ws + 3 * XBYTES + WBYTES);
  unsigned short* wvt   = (unsigned short*)(ws + 3 * XBYTES + 2 * WBYTES);
  unsigned short* wot   = (unsigned short*)(ws + 3 * XBYTES + 3 * WBYTES);
  unsigned short* qp    = (unsigned short*)(ws + 3 * XBYTES + 4 * WBYTES);
  unsigned short* kp    = (unsigned short*)(ws + 4 * XBYTES + 4 * WBYTES);
  unsigned short* vt    = (unsigned short*)(ws + 5 * XBYTES + 4 * WBYTES); // V^T, written by V-GEMM
  unsigned short* ctx   = xq_bf;  // dead after Q projection

  const int nX = MROWS * DM;
  conv3_kernel<<<dim3(nX / 1024, 3), 256, 0, stream>>>(Xq, Xk, Xv, xq_bf, xk_bf, xv_bf);
  trans4_kernel<<<dim3(32, 32, 4), 256, 0, stream>>>(Wq, Wk, Wv, Wo, wqt, wkt, wvt, wot);

  gemm_qkv<<<dim3(DM / 128, MROWS / 128, 3), 256, 0, stream>>>(
      xq_bf, xk_bf, xv_bf, wqt, wkt, wvt, qp, kp, vt);

  attn_kernel<<<dim3(32, BATCH * NHEAD), 256, 0, stream>>>(qp, kp, vt, ctx);

  gemm_out64<<<dim3(DM / 128, MROWS / 64), 256, 0, stream>>>(ctx, wot, out);
}